// Round 1
// baseline (443.731 us; speedup 1.0000x reference)
//
#include <hip/hip_runtime.h>
#include <hip/hip_fp16.h>

// cosFormer linear attention, MI355X. L=S=2048, B=4, E=1024.
// Pipeline: f32->f16 convert; 3 proj GEMMs (fp16 MFMA, fp32 acc, epilogue folds
// bias/relu/sin-cos concat); LDS-tiled transposes to get K-dim contiguous;
// k_sum + z reductions (f32); kv GEMM; attn GEMM (epilogue * z) -> f32 out.

typedef _Float16 f16;
typedef f16 f16x8 __attribute__((ext_vector_type(8)));
typedef f16 f16x4 __attribute__((ext_vector_type(4)));
typedef float f32x4 __attribute__((ext_vector_type(4)));

#define AS1 __attribute__((address_space(1)))
#define AS3 __attribute__((address_space(3)))

__device__ __forceinline__ void gload_lds16(const void* g, void* l) {
  // async global->LDS, 16B/lane; LDS dest = wave-uniform base + lane*16
  __builtin_amdgcn_global_load_lds((const AS1 void*)g, (AS3 void*)l, 16, 0, 0);
}

// ---------------------------------------------------------------------------
// f32 -> f16 convert (vectorized x4)
__global__ void cvt_f32_to_f16(const float* __restrict__ src, f16* __restrict__ dst, int n4) {
  const int i = blockIdx.x * 256 + threadIdx.x;
  if (i >= n4) return;
  const float4 v = ((const float4*)src)[i];
  f16x4 o = { (f16)v.x, (f16)v.y, (f16)v.z, (f16)v.w };
  ((f16x4*)dst)[i] = o;
}

// ---------------------------------------------------------------------------
// Generic 128x128x(BK=64) fp16 MFMA GEMM:  C[m][n] = sum_k A[m][k] * B[n][k]
// Both operands k-contiguous. LDS holds 16 fragment-blocks of 1KB per matrix:
// block(mt,kt) filled so that lane l's 16B = row (mt*16 + (l&15)), k (kt*32 + (l>>4)*8 .. +7)
// -> fragment load is ds_read_b128 at blockbase + lane*16 (conflict-free).
// MODE 0: V proj   -> f16 C = acc + bias
// MODE 1: Q/K proj -> f16 dual write: relu(acc+bias)*sin at col n, *cos at col n+ldc/2
// MODE 2: kv       -> f16 C = acc
// MODE 3: attn     -> f32 C = acc * z[l*4+bz]
template<int MODE>
__launch_bounds__(256)
__global__ void gemm_bt(const f16* __restrict__ A, int lda,
                        const f16* __restrict__ B, int ldb,
                        void* __restrict__ Cout, int K, int ldc,
                        const float* __restrict__ bias,
                        const float* __restrict__ zvec,
                        long abatch, long bbatch, long cbatch)
{
  __shared__ f16 As[16 * 512];   // 16 KB
  __shared__ f16 Bs[16 * 512];   // 16 KB
  const int tid  = threadIdx.x;
  const int lane = tid & 63;
  const int w    = tid >> 6;        // wave 0..3
  const int wm   = w >> 1, wn = w & 1;
  const int bz   = blockIdx.z;
  A += (long)bz * abatch;
  B += (long)bz * bbatch;
  const int m0   = blockIdx.y * 128;
  const int n0   = blockIdx.x * 128;
  const int l15  = lane & 15;
  const int quad = lane >> 4;

  f32x4 acc[4][4] = {};

  // staging pointers: wave w stages fragment-blocks bid = w*4 .. w*4+3 of A and B
  const f16* ag[4];
  const f16* bg[4];
  f16* al[4];
  f16* bl[4];
#pragma unroll
  for (int i = 0; i < 4; ++i) {
    const int bid = w * 4 + i;
    const int mt = bid >> 1;
    const int kt = bid & 1;
    ag[i] = A + (long)(m0 + mt * 16 + l15) * lda + kt * 32 + quad * 8;
    bg[i] = B + (long)(n0 + mt * 16 + l15) * ldb + kt * 32 + quad * 8;
    al[i] = As + bid * 512;
    bl[i] = Bs + bid * 512;
  }

  for (int k0 = 0; k0 < K; k0 += 64) {
#pragma unroll
    for (int i = 0; i < 4; ++i) {
      gload_lds16(ag[i], al[i]);
      gload_lds16(bg[i], bl[i]);
    }
#pragma unroll
    for (int i = 0; i < 4; ++i) { ag[i] += 64; bg[i] += 64; }
    __syncthreads();   // drains vmcnt -> LDS tiles ready
#pragma unroll
    for (int kt = 0; kt < 2; ++kt) {
      f16x8 af[4], bf[4];
#pragma unroll
      for (int i = 0; i < 4; ++i)
        af[i] = *(const f16x8*)(As + ((wm * 4 + i) * 2 + kt) * 512 + lane * 8);
#pragma unroll
      for (int j = 0; j < 4; ++j)
        bf[j] = *(const f16x8*)(Bs + ((wn * 4 + j) * 2 + kt) * 512 + lane * 8);
#pragma unroll
      for (int i = 0; i < 4; ++i)
#pragma unroll
        for (int j = 0; j < 4; ++j)
          acc[i][j] = __builtin_amdgcn_mfma_f32_16x16x32_f16(af[i], bf[j], acc[i][j], 0, 0, 0);
    }
    __syncthreads();   // all waves done reading before next stage
  }

  // Epilogue. C/D layout (verified m89/m91): col = lane&15, row = quad*4 + reg.
  if constexpr (MODE == 0 || MODE == 2) {
    f16* C = (f16*)Cout + (long)bz * cbatch;
#pragma unroll
    for (int i = 0; i < 4; ++i) {
      const int mg = m0 + wm * 64 + i * 16 + quad * 4;
#pragma unroll
      for (int j = 0; j < 4; ++j) {
        const int ng = n0 + wn * 64 + j * 16 + l15;
        const float bc = (MODE == 0) ? bias[ng] : 0.f;
#pragma unroll
        for (int rr = 0; rr < 4; ++rr)
          C[(long)(mg + rr) * ldc + ng] = (f16)(acc[i][j][rr] + bc);
      }
    }
  } else if constexpr (MODE == 1) {
    f16* C = (f16*)Cout;
    const int halfw = ldc >> 1;
#pragma unroll
    for (int i = 0; i < 4; ++i) {
      const int mg = m0 + wm * 64 + i * 16 + quad * 4;
      float sn[4], cn[4];
#pragma unroll
      for (int rr = 0; rr < 4; ++rr) {
        const int l = (mg + rr) >> 2;          // natural row = l*4 + b
        const float ang = 7.6699039394282066e-4f * (float)(l + 1);  // (pi/2)/2048 * (l+1)
        __sincosf(ang, &sn[rr], &cn[rr]);
      }
#pragma unroll
      for (int j = 0; j < 4; ++j) {
        const int ng = n0 + wn * 64 + j * 16 + l15;
        const float bc = bias[ng];
#pragma unroll
        for (int rr = 0; rr < 4; ++rr) {
          const float v = fmaxf(acc[i][j][rr] + bc, 0.f);
          C[(long)(mg + rr) * ldc + ng]         = (f16)(v * sn[rr]);
          C[(long)(mg + rr) * ldc + ng + halfw] = (f16)(v * cn[rr]);
        }
      }
    }
  } else {  // MODE 3: attn, f32 out, scale by z
    float* C = (float*)Cout + (long)bz * cbatch;
#pragma unroll
    for (int i = 0; i < 4; ++i) {
      const int mg = m0 + wm * 64 + i * 16 + quad * 4;
      float zr[4];
#pragma unroll
      for (int rr = 0; rr < 4; ++rr) zr[rr] = zvec[(long)(mg + rr) * 4 + bz];
#pragma unroll
      for (int j = 0; j < 4; ++j) {
        const int ng = n0 + wn * 64 + j * 16 + l15;
#pragma unroll
        for (int rr = 0; rr < 4; ++rr)
          C[(long)(mg + rr) * ldc + ng] = acc[i][j][rr] * zr[rr];
      }
    }
  }
}

// ---------------------------------------------------------------------------
// fp16 64x64 LDS-tiled transpose: out[c][r] = in[r][c], per-batch strides.
__global__ void transpose_f16(const f16* __restrict__ in, f16* __restrict__ out,
                              long in_batch, long out_batch, int ldin, int ldout) {
  __shared__ f16 tile[64 * 72];   // +8 halves pad (keeps 16B alignment: 144B stride)
  const int b = blockIdx.z;
  in  += (long)b * in_batch;
  out += (long)b * out_batch;
  const int r0 = blockIdx.y * 64;
  const int c0 = blockIdx.x * 64;
  const int t  = threadIdx.x;
  {
    const int r = t >> 2, cs = (t & 3) * 16;
    const f16* src = in + (long)(r0 + r) * ldin + c0 + cs;
    f16x8 v0 = *(const f16x8*)(src);
    f16x8 v1 = *(const f16x8*)(src + 8);
    *(f16x8*)(tile + r * 72 + cs)     = v0;
    *(f16x8*)(tile + r * 72 + cs + 8) = v1;
  }
  __syncthreads();
  {
    const int c = t >> 2, rs = (t & 3) * 16;
    alignas(16) f16 tmp[16];
#pragma unroll
    for (int j = 0; j < 16; ++j) tmp[j] = tile[(rs + j) * 72 + c];
    f16* dst = out + (long)(c0 + c) * ldout + r0 + rs;
    *(f16x8*)(dst)     = *(const f16x8*)(tmp);
    *(f16x8*)(dst + 8) = *(const f16x8*)(tmp + 8);
  }
}

// ---------------------------------------------------------------------------
// k_sum[b][d] = sum_s K_t[b][d][s]  (one block per row of 2048)
__global__ void ksum_kernel(const f16* __restrict__ Kt, float* __restrict__ ks) {
  const long row = blockIdx.x;
  const int t = threadIdx.x;
  f16x8 v = *(const f16x8*)(Kt + row * 2048 + t * 8);
  float s = 0.f;
#pragma unroll
  for (int j = 0; j < 8; ++j) s += (float)v[j];
#pragma unroll
  for (int off = 32; off > 0; off >>= 1) s += __shfl_down(s, off, 64);
  __shared__ float red[4];
  if ((t & 63) == 0) red[t >> 6] = s;
  __syncthreads();
  if (t == 0) ks[row] = red[0] + red[1] + red[2] + red[3];
}

// z[r=l*4+b] = 1 / max(sum_d Q_[r][d] * k_sum[b][d], eps)
__global__ void z_kernel(const f16* __restrict__ Qf, const float* __restrict__ ks,
                         float* __restrict__ zb) {
  const long r = blockIdx.x;
  const int t = threadIdx.x;
  const int b = (int)(r & 3);
  f16x8 q = *(const f16x8*)(Qf + r * 2048 + t * 8);
  const float* kp = ks + b * 2048 + t * 8;
  float s = 0.f;
#pragma unroll
  for (int j = 0; j < 8; ++j) s += (float)q[j] * kp[j];
#pragma unroll
  for (int off = 32; off > 0; off >>= 1) s += __shfl_down(s, off, 64);
  __shared__ float red[4];
  if ((t & 63) == 0) red[t >> 6] = s;
  __syncthreads();
  if (t == 0) zb[r] = 1.f / fmaxf(red[0] + red[1] + red[2] + red[3], 1e-6f);
}

// ---------------------------------------------------------------------------
extern "C" void kernel_launch(void* const* d_in, const int* in_sizes, int n_in,
                              void* d_out, int out_size, void* d_ws, size_t ws_size,
                              hipStream_t stream) {
  const float* query = (const float*)d_in[0];
  const float* key_  = (const float*)d_in[1];
  const float* value = (const float*)d_in[2];
  const float* Wq    = (const float*)d_in[3];
  const float* bq    = (const float*)d_in[4];
  const float* Wk    = (const float*)d_in[5];
  const float* bk    = (const float*)d_in[6];
  const float* Wv    = (const float*)d_in[7];
  const float* bv    = (const float*)d_in[8];

  char* ws = (char*)d_ws;
  const size_t MB = 1ull << 20;
  // Workspace layout (peak 134 MB, with lifetime-based aliasing):
  f16* wq16 = (f16*)(ws + 0 * MB);    // 2 MB
  f16* wk16 = (f16*)(ws + 2 * MB);    // 2 MB
  f16* wv16 = (f16*)(ws + 4 * MB);    // 2 MB
  f16* q16  = (f16*)(ws + 6 * MB);    // 16 MB (dead after proj GEMMs)
  f16* k16  = (f16*)(ws + 22 * MB);   // 16 MB (dead after proj GEMMs)
  f16* v16  = (f16*)(ws + 38 * MB);   // 16 MB (dead after proj GEMMs)
  f16* Qf   = (f16*)(ws + 54 * MB);   // 32 MB  Q_ [l*4+b][2048]
  f16* Kn   = (f16*)(ws + 86 * MB);   // 32 MB  K_ natural [s*4+b][2048] (dead after transpose)
  f16* Vp   = (f16*)(ws + 118 * MB);  // 16 MB  V  natural [s*4+b][1024] (dead after transpose)
  f16* Kt   = (f16*)(ws + 6 * MB);    // 32 MB  K_t [b][d][s]   (aliases q16+k16)
  f16* Vt   = (f16*)(ws + 38 * MB);   // 16 MB  V_t [b][m][s]   (aliases v16)
  f16* kvb  = (f16*)(ws + 86 * MB);   // 16 MB  kv  [b][m][d]   (aliases Kn)
  float* ks = (float*)(ws + 102 * MB);  // 32 KB k_sum[b][d]
  float* zb = (float*)(ws + 103 * MB);  // 32 KB z[l*4+b]

  // 1) f32 -> f16
  cvt_f32_to_f16<<<8192, 256, 0, stream>>>(query, q16, 2097152);
  cvt_f32_to_f16<<<8192, 256, 0, stream>>>(key_,  k16, 2097152);
  cvt_f32_to_f16<<<8192, 256, 0, stream>>>(value, v16, 2097152);
  cvt_f32_to_f16<<<1024, 256, 0, stream>>>(Wq, wq16, 262144);
  cvt_f32_to_f16<<<1024, 256, 0, stream>>>(Wk, wk16, 262144);
  cvt_f32_to_f16<<<1024, 256, 0, stream>>>(Wv, wv16, 262144);

  // 2) projections (M=8192, N=1024, K=1024)
  gemm_bt<1><<<dim3(8, 64, 1), 256, 0, stream>>>(q16, 1024, wq16, 1024, Qf, 1024, 2048, bq, nullptr, 0, 0, 0);
  gemm_bt<1><<<dim3(8, 64, 1), 256, 0, stream>>>(k16, 1024, wk16, 1024, Kn, 1024, 2048, bk, nullptr, 0, 0, 0);
  gemm_bt<0><<<dim3(8, 64, 1), 256, 0, stream>>>(v16, 1024, wv16, 1024, Vp, 1024, 1024, bv, nullptr, 0, 0, 0);

  // 3) transposes: K_ [s][d] -> K_t [d][s]; V [s][m] -> V_t [m][s]  (per batch)
  transpose_f16<<<dim3(32, 32, 4), 256, 0, stream>>>(Kn, Kt, 2048, 2048L * 2048, 8192, 2048);
  transpose_f16<<<dim3(16, 32, 4), 256, 0, stream>>>(Vp, Vt, 1024, 1024L * 2048, 4096, 2048);

  // 4) k_sum and z
  ksum_kernel<<<8192, 256, 0, stream>>>(Kt, ks);
  z_kernel<<<8192, 256, 0, stream>>>(Qf, ks, zb);

  // 5) kv[b][m][d] = sum_s V_t[m][s] * K_t[d][s]   (M=1024, N=2048, K=2048)
  gemm_bt<2><<<dim3(16, 8, 4), 256, 0, stream>>>(Vt, 2048, Kt, 2048, kvb, 2048, 2048,
                                                 nullptr, nullptr, 1024L * 2048, 2048L * 2048, 1024L * 2048);
  // 6) attn[l][b][m] = z * sum_d Q_[l][d] * kv[m][d]  (M=2048, N=1024, K=2048), f32 out
  gemm_bt<3><<<dim3(8, 16, 4), 256, 0, stream>>>(Qf, 8192, kvb, 2048, d_out, 2048, 4096,
                                                 nullptr, zb, 2048, 1024L * 2048, 1024);
}